// Round 8
// baseline (354.838 us; speedup 1.0000x reference)
//
#include <hip/hip_runtime.h>
#include <hip/hip_bf16.h>
#include <cstdint>
#include <cstddef>

#define BB 2
#define NN 8192
#define EE 131072
#define FFdim 128
#define HHdim 256
#define NHEAD 4
#define DHEAD 64
#define FEATD 268
#define K1PAD 288        // FEAT padded to multiple of 32
#define SF 296           // feat LDS row stride (ushort)
#define SH 264           // hmid/ef overlay stride (ushort); 528B, 16B-aligned
#define TE 64            // edges per edge-block
#define NT 16            // nodes per node-block (16 -> 1024 blocks -> 4/CU)
#define SA 392           // node A ([h|agg], 384) stride (ushort)
#define SM 264           // node mid overlay stride (ushort)

typedef short bf16x8 __attribute__((ext_vector_type(8)));
typedef float floatx4 __attribute__((ext_vector_type(4)));

__device__ __forceinline__ float silu_f(float x) {
    return x * __fdividef(1.0f, 1.0f + __expf(-x));
}
__device__ __forceinline__ unsigned short f2bf(float x) {
    unsigned int u = __float_as_uint(x);
    unsigned int r = (u + 0x7fffu + ((u >> 16) & 1u)) >> 16;
    return (unsigned short)r;
}
__device__ __forceinline__ float bf2f(unsigned short u) {
    return __uint_as_float(((unsigned int)u) << 16);
}
// packed f32x2 -> bf16x2 (v_cvt_pk_bf16_f32); x lands in low 16 bits
__device__ __forceinline__ unsigned int pk2bf(float x, float y) {
    float2 f = { x, y };
    __hip_bfloat162 t = __float22bfloat162_rn(f);
    union { __hip_bfloat162 b; unsigned int u; } cv;
    cv.b = t;
    return cv.u;
}
// permuted within-64 position p -> original offset (p = lm*4+ct, o = ct*16+lm)
__device__ __forceinline__ int operm(int p) { return ((p & 3) << 4) | (p >> 2); }

// ---------------------------------------------------------------------------
// prep: fp32 weights -> transposed (k-permuted) bf16; h -> bf16; zero counts.
#define W1T_ELEMS (256 * K1PAD)
#define W2T_ELEMS (256 * 64)
#define CW1T_ELEMS (256 * 256)
#define NW1T_ELEMS (256 * 384)
#define NW2T_ELEMS (128 * 256)
#define HBF_ELEMS (BB * NN * FFdim)
#define WT_A (W1T_ELEMS)
#define WT_B (W1T_ELEMS + W2T_ELEMS)
#define WT_C (W1T_ELEMS + W2T_ELEMS + CW1T_ELEMS)
#define WT_D (WT_C + NW1T_ELEMS)
#define WT_E (WT_D + NW2T_ELEMS)
#define WT_F (WT_E + NN)
#define WT_G (WT_F + HBF_ELEMS)
__global__ void prep_weights(const float* __restrict__ w1,
                             const float* __restrict__ w2,
                             const float* __restrict__ cw1,
                             const float* __restrict__ nw1,
                             const float* __restrict__ nw2,
                             const float* __restrict__ h,
                             unsigned short* __restrict__ w1T,
                             unsigned short* __restrict__ w2T,
                             unsigned short* __restrict__ cw1T,
                             unsigned short* __restrict__ nw1T,
                             unsigned short* __restrict__ nw2T,
                             unsigned short* __restrict__ hbf,
                             int* __restrict__ counts) {
    int idx = blockIdx.x * blockDim.x + threadIdx.x;
    if (idx < WT_A) {
        int n = idx / K1PAD, k = idx % K1PAD;
        int hh = n >> 6, d = n & 63;
        float v = (k < FEATD) ? w1[((size_t)hh * FEATD + k) * DHEAD + d] : 0.f;
        w1T[idx] = f2bf(v);
    } else if (idx < WT_B) {
        int j = idx - WT_A;
        int n = j >> 6, p = j & 63;
        int hh = n >> 6, dout = n & 63;
        int din = operm(p);
        w2T[j] = f2bf(w2[(size_t)hh * 4096 + din * 64 + dout]);
    } else if (idx < WT_C) {
        int j = idx - WT_B;
        int n = j >> 8, P = j & 255;
        int ko = (P >> 6) * 64 + operm(P & 63);
        cw1T[j] = f2bf(cw1[ko * 256 + n]);
    } else if (idx < WT_D) {
        int j = idx - WT_C;
        int n = j / 384, k = j % 384;
        int ko = (k < 128) ? k : 128 + ((k - 128) >> 6) * 64 + operm(k & 63);
        nw1T[j] = f2bf(nw1[ko * 256 + n]);
    } else if (idx < WT_E) {
        int j = idx - WT_D;
        int n = j >> 8, P = j & 255;
        int ko = (P >> 6) * 64 + operm(P & 63);
        nw2T[j] = f2bf(nw2[ko * 128 + n]);
    } else if (idx < WT_F) {
        counts[idx - WT_E] = 0;
    } else if (idx < WT_G) {
        int j = idx - WT_F;
        hbf[j] = f2bf(h[j]);
    }
}

// ---------------------------------------------------------------------------
// CSR build (row indices shared across batches)
__global__ void csr_count(const int* __restrict__ eidx, int* __restrict__ counts) {
    int e = blockIdx.x * 256 + threadIdx.x;
    atomicAdd(&counts[eidx[e]], 1);
}

__global__ void csr_scan(const int* __restrict__ counts,
                         int* __restrict__ offsets,
                         int* __restrict__ cursor) {
    __shared__ int wsum[4];
    const int t = threadIdx.x;
    const int base = t * 32;
    int local[32];
    int s = 0;
#pragma unroll
    for (int i = 0; i < 32; ++i) { local[i] = counts[base + i]; s += local[i]; }
    const int lane = t & 63, w = t >> 6;
    int v = s;
#pragma unroll
    for (int off = 1; off < 64; off <<= 1) {
        int u = __shfl_up(v, off, 64);
        if (lane >= off) v += u;
    }
    if (lane == 63) wsum[w] = v;
    __syncthreads();
    int wbase = 0;
    for (int i = 0; i < w; ++i) wbase += wsum[i];
    int run = wbase + v - s;
#pragma unroll
    for (int i = 0; i < 32; ++i) {
        offsets[base + i] = run;
        cursor[base + i] = run;
        run += local[i];
    }
    if (t == 255) offsets[NN] = run;
}

__global__ void csr_fill(const int* __restrict__ eidx,
                         int* __restrict__ cursor, int* __restrict__ perm) {
    int e = blockIdx.x * 256 + threadIdx.x;
    int r = eidx[e];
    int pos = atomicAdd(&cursor[r], 1);
    perm[e] = pos;
}

// ---------------------------------------------------------------------------
// edge kernel (MFMA bf16): one block = 64 edges of one batch, 256 threads.
__global__ __launch_bounds__(256, 4)
void edge_kernel(const unsigned short* __restrict__ hbf,
                 const float* __restrict__ coord,
                 const int* __restrict__ eidx,
                 const int* __restrict__ perm,
                 const unsigned short* __restrict__ w1T, const float* __restrict__ b1,
                 const unsigned short* __restrict__ w2T, const float* __restrict__ b2,
                 const float* __restrict__ lng, const float* __restrict__ lnb,
                 const unsigned short* __restrict__ cw1T, const float* __restrict__ cb1,
                 const float* __restrict__ cw2,
                 unsigned short* __restrict__ efb, float4* __restrict__ wd) {
    __shared__ unsigned short bufA[TE * SF];   // 37888B: feat; then hmid/ef (SH)
    __shared__ int slot_s[TE];                 // 256B
    __shared__ float cd_s[TE][3];              // 768B
    __shared__ float lns[TE], lns2[TE];        // 512B  (LN partial accumulators)
    __shared__ float scr[TE * 4];              // 1024B (mu|rs, later wpart)
    // total 40448B

    const int tid = threadIdx.x;
    const int b = blockIdx.y;
    const int e0 = blockIdx.x * TE;
    const int lane = tid & 63;
    const int w = tid >> 6;          // wave id = column quarter / head
    const int lm = lane & 15;
    const int quad = lane >> 4;
    const int koff = quad * 8;

    // --- phase 1: geometry + slot + LN-acc zero (one thread per edge) ---
    if (tid < TE) {
        lns[tid] = 0.f; lns2[tid] = 0.f;
        const int e = e0 + tid;
        const int r = eidx[e], c = eidx[EE + e];
        slot_s[tid] = perm[e];
        const float* pi = coord + ((size_t)b * NN + r) * 3;
        const float* pk = coord + ((size_t)b * NN + c) * 3;
        float ci0 = pi[0], ci1 = pi[1], ci2 = pi[2];
        float ck0 = pk[0], ck1 = pk[1], ck2 = pk[2];
        float dx = ci0 - ck0, dy = ci1 - ck1, dz = ci2 - ck2;
        float radial = dx * dx + dy * dy + dz * dz;
        float dist = sqrtf(radial);
        float dotv = ci0 * ck0 + ci1 * ck1 + ci2 * ck2;
        float inva = __fdividef(1.0f, dist + 1e-8f);
        float a0 = dx * inva, a1 = dy * inva, a2 = dz * inva;
        float cr0 = ci1 * ck2 - ci2 * ck1;
        float cr1 = ci2 * ck0 - ci0 * ck2;
        float cr2 = ci0 * ck1 - ci1 * ck0;
        float nb = sqrtf(cr0 * cr0 + cr1 * cr1 + cr2 * cr2);
        float invb = __fdividef(1.0f, nb + 1e-8f);
        float b0 = cr0 * invb, b1v = cr1 * invb, b2v = cr2 * invb;
        float c0 = a1 * b2v - a2 * b1v;
        float c1 = a2 * b0 - a0 * b2v;
        float c2 = a0 * b1v - a1 * b0;
        float na = sqrtf(a0 * a0 + a1 * a1 + a2 * a2);
        float nbn = sqrtf(b0 * b0 + b1v * b1v + b2v * b2v);
        float nc = sqrtf(c0 * c0 + c1 * c1 + c2 * c2);
        bool bad = (na < 1e-6f) || (nbn < 1e-6f) || (nc < 1e-6f);
        float s[12];
        s[0] = radial; s[1] = dist; s[2] = dotv;
        if (bad) {
            s[3] = 1.f; s[4] = 0.f; s[5] = 0.f;
            s[6] = 0.f; s[7] = 1.f; s[8] = 0.f;
            s[9] = 0.f; s[10] = 0.f; s[11] = 1.f;
        } else {
            s[3] = a0;  s[4] = b0;  s[5] = c0;
            s[6] = a1;  s[7] = b1v; s[8] = c1;
            s[9] = a2;  s[10] = b2v; s[11] = c2;
        }
        unsigned short* fp = &bufA[tid * SF];
#pragma unroll
        for (int q = 0; q < 12; ++q) fp[256 + q] = f2bf(s[q]);
#pragma unroll
        for (int q = FEATD; q < K1PAD; ++q) fp[q] = 0;
        cd_s[tid][0] = dx; cd_s[tid][1] = dy; cd_s[tid][2] = dz;
    }
    // --- phase 2: gather hbf[row] (cols 0..127) + hbf[col] (cols 128..255) ---
    for (int idx = tid; idx < TE * 32; idx += 256) {
        const int e = idx >> 5, c16 = idx & 31;
        const int node = (c16 < 16) ? eidx[e0 + e] : eidx[EE + e0 + e];
        const int cc = (c16 & 15) * 8;
        uint4 v = *(const uint4*)&hbf[((size_t)b * NN + node) * FFdim + cc];
        *(uint4*)&bufA[e * SF + c16 * 8] = v;
    }
    __syncthreads();

    // --- GEMM1: feat[64 x 288] @ w1T -> hmid[64 x 256], silu ---
    floatx4 acc[4][4];
#pragma unroll
    for (int i = 0; i < 4; ++i)
#pragma unroll
        for (int j = 0; j < 4; ++j)
#pragma unroll
            for (int q = 0; q < 4; ++q) acc[i][j][q] = 0.f;
#pragma unroll
    for (int ks = 0; ks < K1PAD / 32; ++ks) {
        const int kb = ks * 32 + koff;
        bf16x8 a[4], bfr[4];
#pragma unroll
        for (int rt = 0; rt < 4; ++rt)
            a[rt] = *(const bf16x8*)&bufA[(rt * 16 + lm) * SF + kb];
#pragma unroll
        for (int ct = 0; ct < 4; ++ct)
            bfr[ct] = *(const bf16x8*)&w1T[(size_t)(w * 64 + ct * 16 + lm) * K1PAD + kb];
#pragma unroll
        for (int rt = 0; rt < 4; ++rt)
#pragma unroll
            for (int ct = 0; ct < 4; ++ct)
                acc[rt][ct] = __builtin_amdgcn_mfma_f32_16x16x32_bf16(
                    a[rt], bfr[ct], acc[rt][ct], 0, 0, 0);
    }
    float bias1[4];
#pragma unroll
    for (int ct = 0; ct < 4; ++ct) bias1[ct] = b1[w * 64 + ct * 16 + lm];
    __syncthreads();   // feat dead; bufA becomes hmid/ef (stride SH, pi-permuted)
#pragma unroll
    for (int rt = 0; rt < 4; ++rt)
#pragma unroll
        for (int reg = 0; reg < 4; ++reg) {
            const int row = rt * 16 + quad * 4 + reg;
            uint2 pk;
            pk.x = pk2bf(silu_f(acc[rt][0][reg] + bias1[0]),
                         silu_f(acc[rt][1][reg] + bias1[1]));
            pk.y = pk2bf(silu_f(acc[rt][2][reg] + bias1[2]),
                         silu_f(acc[rt][3][reg] + bias1[3]));
            *(uint2*)&bufA[row * SH + w * 64 + lm * 4] = pk;
        }
    // wave-local: wave w's GEMM2 reads only the quarter wave w wrote.

    // --- GEMM2: hmid[:, head w] @ w2T(head w) ---
    floatx4 acc2[4][4];
#pragma unroll
    for (int i = 0; i < 4; ++i)
#pragma unroll
        for (int j = 0; j < 4; ++j)
#pragma unroll
            for (int q = 0; q < 4; ++q) acc2[i][j][q] = 0.f;
#pragma unroll
    for (int ks = 0; ks < 2; ++ks) {
        const int kb = ks * 32 + koff;
        bf16x8 a[4], bfr[4];
#pragma unroll
        for (int rt = 0; rt < 4; ++rt)
            a[rt] = *(const bf16x8*)&bufA[(rt * 16 + lm) * SH + w * 64 + kb];
#pragma unroll
        for (int ct = 0; ct < 4; ++ct)
            bfr[ct] = *(const bf16x8*)&w2T[(size_t)(w * 64 + ct * 16 + lm) * 64 + kb];
#pragma unroll
        for (int rt = 0; rt < 4; ++rt)
#pragma unroll
            for (int ct = 0; ct < 4; ++ct)
                acc2[rt][ct] = __builtin_amdgcn_mfma_f32_16x16x32_bf16(
                    a[rt], bfr[ct], acc2[rt][ct], 0, 0, 0);
    }
    // --- bias + LN partials via LDS atomics ---
    float bias2[4];
#pragma unroll
    for (int ct = 0; ct < 4; ++ct) bias2[ct] = b2[w * 64 + ct * 16 + lm];
#pragma unroll
    for (int rt = 0; rt < 4; ++rt)
#pragma unroll
        for (int reg = 0; reg < 4; ++reg) {
            float s = 0.f, s2 = 0.f;
#pragma unroll
            for (int ct = 0; ct < 4; ++ct) {
                float v = acc2[rt][ct][reg] + bias2[ct];
                acc2[rt][ct][reg] = v;
                s += v; s2 += v * v;
            }
#pragma unroll
            for (int m = 1; m <= 8; m <<= 1) {
                s += __shfl_xor(s, m, 64);
                s2 += __shfl_xor(s2, m, 64);
            }
            if (lm == 0) {
                const int row = rt * 16 + quad * 4 + reg;
                atomicAdd(&lns[row], s);
                atomicAdd(&lns2[row], s2);
            }
        }
    __syncthreads();
    if (tid < TE) {
        float mean = lns[tid] * (1.0f / 256.0f);
        float var = lns2[tid] * (1.0f / 256.0f) - mean * mean;
        scr[tid] = mean;                       // mu
        scr[TE + tid] = rsqrtf(var + 1e-5f);   // rs
    }
    __syncthreads();
    {
        float gv[4], bv[4];
#pragma unroll
        for (int ct = 0; ct < 4; ++ct) {
            const int col = w * 64 + ct * 16 + lm;
            gv[ct] = lng[col]; bv[ct] = lnb[col];
        }
#pragma unroll
        for (int rt = 0; rt < 4; ++rt)
#pragma unroll
            for (int reg = 0; reg < 4; ++reg) {
                const int row = rt * 16 + quad * 4 + reg;
                const float mu = scr[row], rs = scr[TE + row];
                uint2 pk;
                pk.x = pk2bf((acc2[rt][0][reg] - mu) * rs * gv[0] + bv[0],
                             (acc2[rt][1][reg] - mu) * rs * gv[1] + bv[1]);
                pk.y = pk2bf((acc2[rt][2][reg] - mu) * rs * gv[2] + bv[2],
                             (acc2[rt][3][reg] - mu) * rs * gv[3] + bv[3]);
                *(uint2*)&bufA[row * SH + w * 64 + lm * 4] = pk;
            }
    }
    __syncthreads();   // all mu/rs reads done -> scr reusable as wpart

    // --- GEMM3: ef[64 x 256] @ cw1T -> silu -> dot cw2 -> w per edge ---
    floatx4 acc3[4][4];
#pragma unroll
    for (int i = 0; i < 4; ++i)
#pragma unroll
        for (int j = 0; j < 4; ++j)
#pragma unroll
            for (int q = 0; q < 4; ++q) acc3[i][j][q] = 0.f;
#pragma unroll
    for (int ks = 0; ks < 8; ++ks) {
        const int kb = ks * 32 + koff;
        bf16x8 a[4], bfr[4];
#pragma unroll
        for (int rt = 0; rt < 4; ++rt)
            a[rt] = *(const bf16x8*)&bufA[(rt * 16 + lm) * SH + kb];
#pragma unroll
        for (int ct = 0; ct < 4; ++ct)
            bfr[ct] = *(const bf16x8*)&cw1T[(size_t)(w * 64 + ct * 16 + lm) * 256 + kb];
#pragma unroll
        for (int rt = 0; rt < 4; ++rt)
#pragma unroll
            for (int ct = 0; ct < 4; ++ct)
                acc3[rt][ct] = __builtin_amdgcn_mfma_f32_16x16x32_bf16(
                    a[rt], bfr[ct], acc3[rt][ct], 0, 0, 0);
    }
    {
        float cb[4], cwv[4];
#pragma unroll
        for (int ct = 0; ct < 4; ++ct) {
            const int col = w * 64 + ct * 16 + lm;
            cb[ct] = cb1[col]; cwv[ct] = cw2[col];
        }
#pragma unroll
        for (int rt = 0; rt < 4; ++rt)
#pragma unroll
            for (int reg = 0; reg < 4; ++reg) {
                float s = 0.f;
#pragma unroll
                for (int ct = 0; ct < 4; ++ct)
                    s += silu_f(acc3[rt][ct][reg] + cb[ct]) * cwv[ct];
#pragma unroll
                for (int m = 1; m <= 8; m <<= 1) s += __shfl_xor(s, m, 64);
                if (lm == 0) scr[(rt * 16 + quad * 4 + reg) * 4 + w] = s;  // wpart
            }
    }
    __syncthreads();

    // --- streaming outputs to CSR slots ---
    if (tid < TE) {
        float ww = scr[tid * 4] + scr[tid * 4 + 1] + scr[tid * 4 + 2] + scr[tid * 4 + 3];
        float4 o = { cd_s[tid][0] * ww, cd_s[tid][1] * ww, cd_s[tid][2] * ww, 0.f };
        wd[(size_t)b * EE + slot_s[tid]] = o;
    }
    for (int idx = tid; idx < TE * 32; idx += 256) {   // 32 x 16B per row
        const int e = idx >> 5, c = idx & 31;
        uint4 v = *(const uint4*)&bufA[e * SH + c * 8];
        *(uint4*)&efb[((size_t)b * EE + slot_s[e]) * HHdim + c * 8] = v;
    }
}

// ---------------------------------------------------------------------------
// fused gather + node MLP (MFMA bf16): one block = 16 nodes of one batch.
// 1024 blocks -> 4 blocks/CU for maximal gather MLP.
__global__ __launch_bounds__(256, 4)
void node_kernel(const float* __restrict__ h,
                 const unsigned short* __restrict__ hbf,
                 const float* __restrict__ coord,
                 const unsigned short* __restrict__ efb,
                 const float4* __restrict__ wd,
                 const int* __restrict__ offsets,
                 const unsigned short* __restrict__ nw1T, const float* __restrict__ nb1,
                 const unsigned short* __restrict__ nw2T, const float* __restrict__ nb2,
                 float* __restrict__ hout, float* __restrict__ coord_out) {
    __shared__ unsigned short bufN[NT * SA];   // [h|agg] bf16; then mid overlay (SM)

    const int tid = threadIdx.x;
    const int b = blockIdx.y;
    const int n0 = blockIdx.x * NT;
    const int lane = tid & 63;
    const int w = tid >> 6;
    const int lm = lane & 15;
    const int quad = lane >> 4;
    const int koff = quad * 8;

    // stage hbf rows (pure uint4 copies), cols 0..127: NT*16 = 256 chunks
    {
        const int r = tid >> 4, c8 = tid & 15;
        uint4 v = *(const uint4*)&hbf[((size_t)b * NN + n0 + r) * FFdim + c8 * 8];
        *(uint4*)&bufN[r * SA + c8 * 8] = v;
    }

    // gather: wave w handles nodes w*4 .. w*4+3 (slot ranges contiguous)
    for (int i = 0; i < 4; ++i) {
        const int r = w * 4 + i;
        const int n = n0 + r;
        const int o0 = offsets[n], o1 = offsets[n + 1];
        float a0 = 0.f, a1 = 0.f, a2 = 0.f, a3 = 0.f;
        const unsigned short* ebase = efb + (size_t)b * EE * HHdim + lane * 4;
        int j = o0;
        for (; j + 8 <= o1; j += 8) {
            ushort4 u[8];
#pragma unroll
            for (int q = 0; q < 8; ++q)
                u[q] = *(const ushort4*)(ebase + (size_t)(j + q) * HHdim);
#pragma unroll
            for (int q = 0; q < 8; ++q) {
                a0 += bf2f(u[q].x); a1 += bf2f(u[q].y);
                a2 += bf2f(u[q].z); a3 += bf2f(u[q].w);
            }
        }
        for (; j < o1; ++j) {
            ushort4 u = *(const ushort4*)(ebase + (size_t)j * HHdim);
            a0 += bf2f(u.x); a1 += bf2f(u.y); a2 += bf2f(u.z); a3 += bf2f(u.w);
        }
        uint2 pk;
        pk.x = pk2bf(a0, a1);
        pk.y = pk2bf(a2, a3);
        *(uint2*)&bufN[r * SA + FFdim + lane * 4] = pk;

        // coord_out = coord + sum(wd)
        float sx = 0.f, sy = 0.f, sz = 0.f;
        for (int jj = o0 + lane; jj < o1; jj += 64) {
            float4 t = wd[(size_t)b * EE + jj];
            sx += t.x; sy += t.y; sz += t.z;
        }
#pragma unroll
        for (int m = 1; m < 64; m <<= 1) {
            sx += __shfl_xor(sx, m, 64);
            sy += __shfl_xor(sy, m, 64);
            sz += __shfl_xor(sz, m, 64);
        }
        if (lane < 3) {
            const size_t cb = ((size_t)b * NN + n) * 3 + lane;
            float s = (lane == 0) ? sx : (lane == 1) ? sy : sz;
            coord_out[cb] = coord[cb] + s;
        }
    }
    __syncthreads();

    // GEMM-A: [h|agg][16 x 384] @ nw1T -> mid[16 x 256], silu (pi-packed store)
    floatx4 acc[4];
#pragma unroll
    for (int j = 0; j < 4; ++j)
#pragma unroll
        for (int q = 0; q < 4; ++q) acc[j][q] = 0.f;
#pragma unroll
    for (int ks = 0; ks < 12; ++ks) {
        const int kb = ks * 32 + koff;
        bf16x8 a = *(const bf16x8*)&bufN[lm * SA + kb];
        bf16x8 bfr[4];
#pragma unroll
        for (int ct = 0; ct < 4; ++ct)
            bfr[ct] = *(const bf16x8*)&nw1T[(size_t)(w * 64 + ct * 16 + lm) * 384 + kb];
#pragma unroll
        for (int ct = 0; ct < 4; ++ct)
            acc[ct] = __builtin_amdgcn_mfma_f32_16x16x32_bf16(a, bfr[ct], acc[ct], 0, 0, 0);
    }
    float nb1v[4];
#pragma unroll
    for (int ct = 0; ct < 4; ++ct) nb1v[ct] = nb1[w * 64 + ct * 16 + lm];
    __syncthreads();   // A dead; overlay mid (stride SM, pi-permuted)
#pragma unroll
    for (int reg = 0; reg < 4; ++reg) {
        const int row = quad * 4 + reg;
        uint2 pk;
        pk.x = pk2bf(silu_f(acc[0][reg] + nb1v[0]), silu_f(acc[1][reg] + nb1v[1]));
        pk.y = pk2bf(silu_f(acc[2][reg] + nb1v[2]), silu_f(acc[3][reg] + nb1v[3]));
        *(uint2*)&bufN[row * SM + w * 64 + lm * 4] = pk;
    }
    __syncthreads();

    // GEMM-B: mid[16 x 256] @ nw2T -> out[16 x 128] + bias + residual
    floatx4 accb[2];
#pragma unroll
    for (int j = 0; j < 2; ++j)
#pragma unroll
        for (int q = 0; q < 4; ++q) accb[j][q] = 0.f;
#pragma unroll
    for (int ks = 0; ks < 8; ++ks) {
        const int kb = ks * 32 + koff;
        bf16x8 a = *(const bf16x8*)&bufN[lm * SM + kb];
        bf16x8 bfr[2];
#pragma unroll
        for (int ct = 0; ct < 2; ++ct)
            bfr[ct] = *(const bf16x8*)&nw2T[(size_t)(w * 32 + ct * 16 + lm) * 256 + kb];
#pragma unroll
        for (int ct = 0; ct < 2; ++ct)
            accb[ct] = __builtin_amdgcn_mfma_f32_16x16x32_bf16(a, bfr[ct], accb[ct], 0, 0, 0);
    }
#pragma unroll
    for (int ct = 0; ct < 2; ++ct) {
        const int col = w * 32 + ct * 16 + lm;
        const float bias = nb2[col];
#pragma unroll
        for (int reg = 0; reg < 4; ++reg) {
            const int row = quad * 4 + reg;
            const size_t gi = ((size_t)b * NN + n0 + row) * FFdim + col;
            hout[gi] = accb[ct][reg] + bias + h[gi];
        }
    }
}

// ---------------------------------------------------------------------------
extern "C" void kernel_launch(void* const* d_in, const int* in_sizes, int n_in,
                              void* d_out, int out_size, void* d_ws, size_t ws_size,
                              hipStream_t stream) {
    const float* h     = (const float*)d_in[0];
    const float* coord = (const float*)d_in[1];
    const int*   eidx  = (const int*)d_in[2];
    const float* w1    = (const float*)d_in[3];
    const float* b1    = (const float*)d_in[4];
    const float* w2    = (const float*)d_in[5];
    const float* b2    = (const float*)d_in[6];
    const float* lng   = (const float*)d_in[7];
    const float* lnb   = (const float*)d_in[8];
    const float* nw1   = (const float*)d_in[9];
    const float* nb1   = (const float*)d_in[10];
    const float* nw2   = (const float*)d_in[11];
    const float* nb2   = (const float*)d_in[12];
    const float* cw1   = (const float*)d_in[13];
    const float* cb1   = (const float*)d_in[14];
    const float* cw2   = (const float*)d_in[15];

    float* hout = (float*)d_out;
    float* coord_out = hout + (size_t)BB * NN * FFdim;

    char* p = (char*)d_ws;
    float4* wd = (float4*)p;                   p += (size_t)BB * EE * 16;          // 4 MB
    unsigned short* efb = (unsigned short*)p;  p += (size_t)BB * EE * HHdim * 2;   // 134 MB
    unsigned short* hbf = (unsigned short*)p;  p += (size_t)HBF_ELEMS * 2;         // 4 MB
    unsigned short* w1T = (unsigned short*)p;  p += (size_t)W1T_ELEMS * 2;
    unsigned short* w2T = (unsigned short*)p;  p += (size_t)W2T_ELEMS * 2;
    unsigned short* cw1T = (unsigned short*)p; p += (size_t)CW1T_ELEMS * 2;
    unsigned short* nw1T = (unsigned short*)p; p += (size_t)NW1T_ELEMS * 2;
    unsigned short* nw2T = (unsigned short*)p; p += (size_t)NW2T_ELEMS * 2;
    int* counts = (int*)p;                     p += (size_t)NN * 4;
    int* offsets = (int*)p;                    p += (size_t)(NN + 1) * 4;
    int* cursor = (int*)p;                     p += (size_t)NN * 4;
    int* perm = (int*)p;                       p += (size_t)EE * 4;

    hipLaunchKernelGGL(prep_weights, dim3((WT_G + 255) / 256), dim3(256),
                       0, stream, w1, w2, cw1, nw1, nw2, h,
                       w1T, w2T, cw1T, nw1T, nw2T, hbf, counts);
    hipLaunchKernelGGL(csr_count, dim3(EE / 256), dim3(256), 0, stream, eidx, counts);
    hipLaunchKernelGGL(csr_scan, dim3(1), dim3(256), 0, stream, counts, offsets, cursor);
    hipLaunchKernelGGL(csr_fill, dim3(EE / 256), dim3(256), 0, stream, eidx, cursor, perm);
    hipLaunchKernelGGL(edge_kernel, dim3(EE / TE, BB), dim3(256), 0, stream,
                       hbf, coord, eidx, perm, w1T, b1, w2T, b2, lng, lnb, cw1T, cb1, cw2,
                       efb, wd);
    hipLaunchKernelGGL(node_kernel, dim3(NN / NT, BB), dim3(256), 0, stream,
                       h, hbf, coord, efb, wd, offsets, nw1T, nb1, nw2T, nb2,
                       hout, coord_out);
}

// Round 9
// 343.814 us; speedup vs baseline: 1.0321x; 1.0321x over previous
//
#include <hip/hip_runtime.h>
#include <hip/hip_bf16.h>
#include <cstdint>
#include <cstddef>

#define BB 2
#define NN 8192
#define EE 131072
#define FFdim 128
#define HHdim 256
#define NHEAD 4
#define DHEAD 64
#define FEATD 268
#define K1PAD 288        // FEAT padded to multiple of 32
#define SF 296           // feat LDS row stride (ushort)
#define SH 264           // hmid/ef overlay stride (ushort); 528B, 16B-aligned
#define TE 64            // edges per edge-block
#define NT 32            // nodes per node-block (R7-proven)
#define SA 392           // node A ([h|agg], 384) stride (ushort)
#define SM 264           // node mid overlay stride (ushort)

typedef short bf16x8 __attribute__((ext_vector_type(8)));
typedef float floatx4 __attribute__((ext_vector_type(4)));

__device__ __forceinline__ float silu_f(float x) {
    return x * __fdividef(1.0f, 1.0f + __expf(-x));
}
__device__ __forceinline__ unsigned short f2bf(float x) {
    unsigned int u = __float_as_uint(x);
    unsigned int r = (u + 0x7fffu + ((u >> 16) & 1u)) >> 16;
    return (unsigned short)r;
}
__device__ __forceinline__ float bf2f(unsigned short u) {
    return __uint_as_float(((unsigned int)u) << 16);
}
// packed f32x2 -> bf16x2 (v_cvt_pk_bf16_f32); x lands in low 16 bits
__device__ __forceinline__ unsigned int pk2bf(float x, float y) {
    float2 f = { x, y };
    __hip_bfloat162 t = __float22bfloat162_rn(f);
    union { __hip_bfloat162 b; unsigned int u; } cv;
    cv.b = t;
    return cv.u;
}
// sum across each 16-lane DPP row via row_ror — VALU-only (no ds_swizzle).
__device__ __forceinline__ float rowsum16(float v) {
    v += __int_as_float(__builtin_amdgcn_update_dpp(0, __float_as_int(v), 0x128, 0xf, 0xf, true));
    v += __int_as_float(__builtin_amdgcn_update_dpp(0, __float_as_int(v), 0x124, 0xf, 0xf, true));
    v += __int_as_float(__builtin_amdgcn_update_dpp(0, __float_as_int(v), 0x122, 0xf, 0xf, true));
    v += __int_as_float(__builtin_amdgcn_update_dpp(0, __float_as_int(v), 0x121, 0xf, 0xf, true));
    return v;
}
// permuted within-64 position p -> original offset (p = lm*4+ct, o = ct*16+lm)
__device__ __forceinline__ int operm(int p) { return ((p & 3) << 4) | (p >> 2); }

// ---------------------------------------------------------------------------
// prep: fp32 weights -> transposed (k-permuted) bf16; h -> bf16; zero counts.
#define W1T_ELEMS (256 * K1PAD)
#define W2T_ELEMS (256 * 64)
#define CW1T_ELEMS (256 * 256)
#define NW1T_ELEMS (256 * 384)
#define NW2T_ELEMS (128 * 256)
#define HBF_ELEMS (BB * NN * FFdim)
#define WT_A (W1T_ELEMS)
#define WT_B (W1T_ELEMS + W2T_ELEMS)
#define WT_C (W1T_ELEMS + W2T_ELEMS + CW1T_ELEMS)
#define WT_D (WT_C + NW1T_ELEMS)
#define WT_E (WT_D + NW2T_ELEMS)
#define WT_F (WT_E + NN)
#define WT_G (WT_F + HBF_ELEMS)
__global__ void prep_weights(const float* __restrict__ w1,
                             const float* __restrict__ w2,
                             const float* __restrict__ cw1,
                             const float* __restrict__ nw1,
                             const float* __restrict__ nw2,
                             const float* __restrict__ h,
                             unsigned short* __restrict__ w1T,
                             unsigned short* __restrict__ w2T,
                             unsigned short* __restrict__ cw1T,
                             unsigned short* __restrict__ nw1T,
                             unsigned short* __restrict__ nw2T,
                             unsigned short* __restrict__ hbf,
                             int* __restrict__ counts) {
    int idx = blockIdx.x * blockDim.x + threadIdx.x;
    if (idx < WT_A) {
        int n = idx / K1PAD, k = idx % K1PAD;
        int hh = n >> 6, d = n & 63;
        float v = (k < FEATD) ? w1[((size_t)hh * FEATD + k) * DHEAD + d] : 0.f;
        w1T[idx] = f2bf(v);
    } else if (idx < WT_B) {
        int j = idx - WT_A;
        int n = j >> 6, p = j & 63;
        int hh = n >> 6, dout = n & 63;
        int din = operm(p);
        w2T[j] = f2bf(w2[(size_t)hh * 4096 + din * 64 + dout]);
    } else if (idx < WT_C) {
        int j = idx - WT_B;
        int n = j >> 8, P = j & 255;
        int ko = (P >> 6) * 64 + operm(P & 63);
        cw1T[j] = f2bf(cw1[ko * 256 + n]);
    } else if (idx < WT_D) {
        int j = idx - WT_C;
        int n = j / 384, k = j % 384;
        int ko = (k < 128) ? k : 128 + ((k - 128) >> 6) * 64 + operm(k & 63);
        nw1T[j] = f2bf(nw1[ko * 256 + n]);
    } else if (idx < WT_E) {
        int j = idx - WT_D;
        int n = j >> 8, P = j & 255;
        int ko = (P >> 6) * 64 + operm(P & 63);
        nw2T[j] = f2bf(nw2[ko * 128 + n]);
    } else if (idx < WT_F) {
        counts[idx - WT_E] = 0;
    } else if (idx < WT_G) {
        int j = idx - WT_F;
        hbf[j] = f2bf(h[j]);
    }
}

// ---------------------------------------------------------------------------
// CSR build (row indices shared across batches)
__global__ void csr_count(const int* __restrict__ eidx, int* __restrict__ counts) {
    int e = blockIdx.x * 256 + threadIdx.x;
    atomicAdd(&counts[eidx[e]], 1);
}

__global__ void csr_scan(const int* __restrict__ counts,
                         int* __restrict__ offsets,
                         int* __restrict__ cursor) {
    __shared__ int wsum[4];
    const int t = threadIdx.x;
    const int base = t * 32;
    int local[32];
    int s = 0;
#pragma unroll
    for (int i = 0; i < 32; ++i) { local[i] = counts[base + i]; s += local[i]; }
    const int lane = t & 63, w = t >> 6;
    int v = s;
#pragma unroll
    for (int off = 1; off < 64; off <<= 1) {
        int u = __shfl_up(v, off, 64);
        if (lane >= off) v += u;
    }
    if (lane == 63) wsum[w] = v;
    __syncthreads();
    int wbase = 0;
    for (int i = 0; i < w; ++i) wbase += wsum[i];
    int run = wbase + v - s;
#pragma unroll
    for (int i = 0; i < 32; ++i) {
        offsets[base + i] = run;
        cursor[base + i] = run;
        run += local[i];
    }
    if (t == 255) offsets[NN] = run;
}

__global__ void csr_fill(const int* __restrict__ eidx,
                         int* __restrict__ cursor, int* __restrict__ perm) {
    int e = blockIdx.x * 256 + threadIdx.x;
    int r = eidx[e];
    int pos = atomicAdd(&cursor[r], 1);
    perm[e] = pos;
}

// ---------------------------------------------------------------------------
// edge kernel (MFMA bf16): one block = 64 edges of one batch, 256 threads.
// Reductions via DPP row_ror (VALU) — the LDS pipe serves only staging+frags.
__global__ __launch_bounds__(256, 4)
void edge_kernel(const unsigned short* __restrict__ hbf,
                 const float* __restrict__ coord,
                 const int* __restrict__ eidx,
                 const int* __restrict__ perm,
                 const unsigned short* __restrict__ w1T, const float* __restrict__ b1,
                 const unsigned short* __restrict__ w2T, const float* __restrict__ b2,
                 const float* __restrict__ lng, const float* __restrict__ lnb,
                 const unsigned short* __restrict__ cw1T, const float* __restrict__ cb1,
                 const float* __restrict__ cw2,
                 unsigned short* __restrict__ efb, float4* __restrict__ wd) {
    __shared__ unsigned short bufA[TE * SF];   // 37888B: feat; then hmid/ef (SH)
    __shared__ int slot_s[TE];                 // 256B
    __shared__ float cd_s[TE][3];              // 768B
    __shared__ float lns[TE], lns2[TE];        // 512B  (LN partial accumulators)
    __shared__ float scr[TE * 4];              // 1024B (mu|rs, later wpart)
    // total 40448B

    const int tid = threadIdx.x;
    const int b = blockIdx.y;
    const int e0 = blockIdx.x * TE;
    const int lane = tid & 63;
    const int w = tid >> 6;          // wave id = column quarter / head
    const int lm = lane & 15;
    const int quad = lane >> 4;
    const int koff = quad * 8;

    // --- phase 1: geometry + slot + LN-acc zero (one thread per edge) ---
    if (tid < TE) {
        lns[tid] = 0.f; lns2[tid] = 0.f;
        const int e = e0 + tid;
        const int r = eidx[e], c = eidx[EE + e];
        slot_s[tid] = perm[e];
        const float* pi = coord + ((size_t)b * NN + r) * 3;
        const float* pk = coord + ((size_t)b * NN + c) * 3;
        float ci0 = pi[0], ci1 = pi[1], ci2 = pi[2];
        float ck0 = pk[0], ck1 = pk[1], ck2 = pk[2];
        float dx = ci0 - ck0, dy = ci1 - ck1, dz = ci2 - ck2;
        float radial = dx * dx + dy * dy + dz * dz;
        float dist = sqrtf(radial);
        float dotv = ci0 * ck0 + ci1 * ck1 + ci2 * ck2;
        float inva = __fdividef(1.0f, dist + 1e-8f);
        float a0 = dx * inva, a1 = dy * inva, a2 = dz * inva;
        float cr0 = ci1 * ck2 - ci2 * ck1;
        float cr1 = ci2 * ck0 - ci0 * ck2;
        float cr2 = ci0 * ck1 - ci1 * ck0;
        float nb = sqrtf(cr0 * cr0 + cr1 * cr1 + cr2 * cr2);
        float invb = __fdividef(1.0f, nb + 1e-8f);
        float b0 = cr0 * invb, b1v = cr1 * invb, b2v = cr2 * invb;
        float c0 = a1 * b2v - a2 * b1v;
        float c1 = a2 * b0 - a0 * b2v;
        float c2 = a0 * b1v - a1 * b0;
        float na = sqrtf(a0 * a0 + a1 * a1 + a2 * a2);
        float nbn = sqrtf(b0 * b0 + b1v * b1v + b2v * b2v);
        float nc = sqrtf(c0 * c0 + c1 * c1 + c2 * c2);
        bool bad = (na < 1e-6f) || (nbn < 1e-6f) || (nc < 1e-6f);
        float s[12];
        s[0] = radial; s[1] = dist; s[2] = dotv;
        if (bad) {
            s[3] = 1.f; s[4] = 0.f; s[5] = 0.f;
            s[6] = 0.f; s[7] = 1.f; s[8] = 0.f;
            s[9] = 0.f; s[10] = 0.f; s[11] = 1.f;
        } else {
            s[3] = a0;  s[4] = b0;  s[5] = c0;
            s[6] = a1;  s[7] = b1v; s[8] = c1;
            s[9] = a2;  s[10] = b2v; s[11] = c2;
        }
        unsigned short* fp = &bufA[tid * SF];
#pragma unroll
        for (int q = 0; q < 12; ++q) fp[256 + q] = f2bf(s[q]);
#pragma unroll
        for (int q = FEATD; q < K1PAD; ++q) fp[q] = 0;
        cd_s[tid][0] = dx; cd_s[tid][1] = dy; cd_s[tid][2] = dz;
    }
    // --- phase 2: gather hbf[row] (cols 0..127) + hbf[col] (cols 128..255) ---
    for (int idx = tid; idx < TE * 32; idx += 256) {
        const int e = idx >> 5, c16 = idx & 31;
        const int node = (c16 < 16) ? eidx[e0 + e] : eidx[EE + e0 + e];
        const int cc = (c16 & 15) * 8;
        uint4 v = *(const uint4*)&hbf[((size_t)b * NN + node) * FFdim + cc];
        *(uint4*)&bufA[e * SF + c16 * 8] = v;
    }
    __syncthreads();

    // --- GEMM1: feat[64 x 288] @ w1T -> hmid[64 x 256], silu ---
    floatx4 acc[4][4];
#pragma unroll
    for (int i = 0; i < 4; ++i)
#pragma unroll
        for (int j = 0; j < 4; ++j)
#pragma unroll
            for (int q = 0; q < 4; ++q) acc[i][j][q] = 0.f;
#pragma unroll
    for (int ks = 0; ks < K1PAD / 32; ++ks) {
        const int kb = ks * 32 + koff;
        bf16x8 a[4], bfr[4];
#pragma unroll
        for (int rt = 0; rt < 4; ++rt)
            a[rt] = *(const bf16x8*)&bufA[(rt * 16 + lm) * SF + kb];
#pragma unroll
        for (int ct = 0; ct < 4; ++ct)
            bfr[ct] = *(const bf16x8*)&w1T[(size_t)(w * 64 + ct * 16 + lm) * K1PAD + kb];
#pragma unroll
        for (int rt = 0; rt < 4; ++rt)
#pragma unroll
            for (int ct = 0; ct < 4; ++ct)
                acc[rt][ct] = __builtin_amdgcn_mfma_f32_16x16x32_bf16(
                    a[rt], bfr[ct], acc[rt][ct], 0, 0, 0);
    }
    float bias1[4];
#pragma unroll
    for (int ct = 0; ct < 4; ++ct) bias1[ct] = b1[w * 64 + ct * 16 + lm];
    __syncthreads();   // feat dead; bufA becomes hmid/ef (stride SH, pi-permuted)
#pragma unroll
    for (int rt = 0; rt < 4; ++rt)
#pragma unroll
        for (int reg = 0; reg < 4; ++reg) {
            const int row = rt * 16 + quad * 4 + reg;
            uint2 pk;
            pk.x = pk2bf(silu_f(acc[rt][0][reg] + bias1[0]),
                         silu_f(acc[rt][1][reg] + bias1[1]));
            pk.y = pk2bf(silu_f(acc[rt][2][reg] + bias1[2]),
                         silu_f(acc[rt][3][reg] + bias1[3]));
            *(uint2*)&bufA[row * SH + w * 64 + lm * 4] = pk;
        }
    // wave-local: wave w's GEMM2 reads only the quarter wave w wrote.

    // --- GEMM2: hmid[:, head w] @ w2T(head w) ---
    floatx4 acc2[4][4];
#pragma unroll
    for (int i = 0; i < 4; ++i)
#pragma unroll
        for (int j = 0; j < 4; ++j)
#pragma unroll
            for (int q = 0; q < 4; ++q) acc2[i][j][q] = 0.f;
#pragma unroll
    for (int ks = 0; ks < 2; ++ks) {
        const int kb = ks * 32 + koff;
        bf16x8 a[4], bfr[4];
#pragma unroll
        for (int rt = 0; rt < 4; ++rt)
            a[rt] = *(const bf16x8*)&bufA[(rt * 16 + lm) * SH + w * 64 + kb];
#pragma unroll
        for (int ct = 0; ct < 4; ++ct)
            bfr[ct] = *(const bf16x8*)&w2T[(size_t)(w * 64 + ct * 16 + lm) * 64 + kb];
#pragma unroll
        for (int rt = 0; rt < 4; ++rt)
#pragma unroll
            for (int ct = 0; ct < 4; ++ct)
                acc2[rt][ct] = __builtin_amdgcn_mfma_f32_16x16x32_bf16(
                    a[rt], bfr[ct], acc2[rt][ct], 0, 0, 0);
    }
    // --- bias + LN partials: DPP row-reduce, then one LDS atomic per row ---
    float bias2[4];
#pragma unroll
    for (int ct = 0; ct < 4; ++ct) bias2[ct] = b2[w * 64 + ct * 16 + lm];
#pragma unroll
    for (int rt = 0; rt < 4; ++rt)
#pragma unroll
        for (int reg = 0; reg < 4; ++reg) {
            float s = 0.f, s2 = 0.f;
#pragma unroll
            for (int ct = 0; ct < 4; ++ct) {
                float v = acc2[rt][ct][reg] + bias2[ct];
                acc2[rt][ct][reg] = v;
                s += v; s2 += v * v;
            }
            s = rowsum16(s);
            s2 = rowsum16(s2);
            if (lm == 0) {
                const int row = rt * 16 + quad * 4 + reg;
                atomicAdd(&lns[row], s);
                atomicAdd(&lns2[row], s2);
            }
        }
    __syncthreads();
    if (tid < TE) {
        float mean = lns[tid] * (1.0f / 256.0f);
        float var = lns2[tid] * (1.0f / 256.0f) - mean * mean;
        scr[tid] = mean;                       // mu
        scr[TE + tid] = rsqrtf(var + 1e-5f);   // rs
    }
    __syncthreads();
    {
        float gv[4], bv[4];
#pragma unroll
        for (int ct = 0; ct < 4; ++ct) {
            const int col = w * 64 + ct * 16 + lm;
            gv[ct] = lng[col]; bv[ct] = lnb[col];
        }
#pragma unroll
        for (int rt = 0; rt < 4; ++rt)
#pragma unroll
            for (int reg = 0; reg < 4; ++reg) {
                const int row = rt * 16 + quad * 4 + reg;
                const float mu = scr[row], rs = scr[TE + row];
                uint2 pk;
                pk.x = pk2bf((acc2[rt][0][reg] - mu) * rs * gv[0] + bv[0],
                             (acc2[rt][1][reg] - mu) * rs * gv[1] + bv[1]);
                pk.y = pk2bf((acc2[rt][2][reg] - mu) * rs * gv[2] + bv[2],
                             (acc2[rt][3][reg] - mu) * rs * gv[3] + bv[3]);
                *(uint2*)&bufA[row * SH + w * 64 + lm * 4] = pk;
            }
    }
    __syncthreads();   // all mu/rs reads done -> scr reusable as wpart

    // --- GEMM3: ef[64 x 256] @ cw1T -> silu -> dot cw2 -> w per edge ---
    floatx4 acc3[4][4];
#pragma unroll
    for (int i = 0; i < 4; ++i)
#pragma unroll
        for (int j = 0; j < 4; ++j)
#pragma unroll
            for (int q = 0; q < 4; ++q) acc3[i][j][q] = 0.f;
#pragma unroll
    for (int ks = 0; ks < 8; ++ks) {
        const int kb = ks * 32 + koff;
        bf16x8 a[4], bfr[4];
#pragma unroll
        for (int rt = 0; rt < 4; ++rt)
            a[rt] = *(const bf16x8*)&bufA[(rt * 16 + lm) * SH + kb];
#pragma unroll
        for (int ct = 0; ct < 4; ++ct)
            bfr[ct] = *(const bf16x8*)&cw1T[(size_t)(w * 64 + ct * 16 + lm) * 256 + kb];
#pragma unroll
        for (int rt = 0; rt < 4; ++rt)
#pragma unroll
            for (int ct = 0; ct < 4; ++ct)
                acc3[rt][ct] = __builtin_amdgcn_mfma_f32_16x16x32_bf16(
                    a[rt], bfr[ct], acc3[rt][ct], 0, 0, 0);
    }
    {
        float cb[4], cwv[4];
#pragma unroll
        for (int ct = 0; ct < 4; ++ct) {
            const int col = w * 64 + ct * 16 + lm;
            cb[ct] = cb1[col]; cwv[ct] = cw2[col];
        }
#pragma unroll
        for (int rt = 0; rt < 4; ++rt)
#pragma unroll
            for (int reg = 0; reg < 4; ++reg) {
                float s = 0.f;
#pragma unroll
                for (int ct = 0; ct < 4; ++ct)
                    s += silu_f(acc3[rt][ct][reg] + cb[ct]) * cwv[ct];
                s = rowsum16(s);
                if (lm == 0) scr[(rt * 16 + quad * 4 + reg) * 4 + w] = s;  // wpart
            }
    }
    __syncthreads();

    // --- streaming outputs to CSR slots ---
    if (tid < TE) {
        float ww = scr[tid * 4] + scr[tid * 4 + 1] + scr[tid * 4 + 2] + scr[tid * 4 + 3];
        float4 o = { cd_s[tid][0] * ww, cd_s[tid][1] * ww, cd_s[tid][2] * ww, 0.f };
        wd[(size_t)b * EE + slot_s[tid]] = o;
    }
    for (int idx = tid; idx < TE * 32; idx += 256) {   // 32 x 16B per row
        const int e = idx >> 5, c = idx & 31;
        uint4 v = *(const uint4*)&bufA[e * SH + c * 8];
        *(uint4*)&efb[((size_t)b * EE + slot_s[e]) * HHdim + c * 8] = v;
    }
}

// ---------------------------------------------------------------------------
// fused gather + node MLP (MFMA bf16): one block = 32 nodes of one batch.
__global__ __launch_bounds__(256, 4)
void node_kernel(const float* __restrict__ h,
                 const unsigned short* __restrict__ hbf,
                 const float* __restrict__ coord,
                 const unsigned short* __restrict__ efb,
                 const float4* __restrict__ wd,
                 const int* __restrict__ offsets,
                 const unsigned short* __restrict__ nw1T, const float* __restrict__ nb1,
                 const unsigned short* __restrict__ nw2T, const float* __restrict__ nb2,
                 float* __restrict__ hout, float* __restrict__ coord_out) {
    __shared__ unsigned short bufN[NT * SA];   // [h|agg] bf16; then mid overlay (SM)

    const int tid = threadIdx.x;
    const int b = blockIdx.y;
    const int n0 = blockIdx.x * NT;
    const int lane = tid & 63;
    const int w = tid >> 6;
    const int lm = lane & 15;
    const int quad = lane >> 4;
    const int koff = quad * 8;

    // stage hbf rows (pure uint4 copies), cols 0..127
    for (int idx = tid; idx < NT * 16; idx += 256) {
        const int r = idx >> 4, c8 = idx & 15;
        uint4 v = *(const uint4*)&hbf[((size_t)b * NN + n0 + r) * FFdim + c8 * 8];
        *(uint4*)&bufN[r * SA + c8 * 8] = v;
    }

    // gather: wave w handles nodes w*8 .. w*8+7 (slot ranges contiguous)
    for (int i = 0; i < 8; ++i) {
        const int r = w * 8 + i;
        const int n = n0 + r;
        const int o0 = offsets[n], o1 = offsets[n + 1];
        float a0 = 0.f, a1 = 0.f, a2 = 0.f, a3 = 0.f;
        const unsigned short* ebase = efb + (size_t)b * EE * HHdim + lane * 4;
        int j = o0;
        for (; j + 4 <= o1; j += 4) {
            ushort4 u0 = *(const ushort4*)(ebase + (size_t)(j + 0) * HHdim);
            ushort4 u1 = *(const ushort4*)(ebase + (size_t)(j + 1) * HHdim);
            ushort4 u2 = *(const ushort4*)(ebase + (size_t)(j + 2) * HHdim);
            ushort4 u3 = *(const ushort4*)(ebase + (size_t)(j + 3) * HHdim);
            a0 += bf2f(u0.x) + bf2f(u1.x) + bf2f(u2.x) + bf2f(u3.x);
            a1 += bf2f(u0.y) + bf2f(u1.y) + bf2f(u2.y) + bf2f(u3.y);
            a2 += bf2f(u0.z) + bf2f(u1.z) + bf2f(u2.z) + bf2f(u3.z);
            a3 += bf2f(u0.w) + bf2f(u1.w) + bf2f(u2.w) + bf2f(u3.w);
        }
        for (; j < o1; ++j) {
            ushort4 u = *(const ushort4*)(ebase + (size_t)j * HHdim);
            a0 += bf2f(u.x); a1 += bf2f(u.y); a2 += bf2f(u.z); a3 += bf2f(u.w);
        }
        uint2 pk;
        pk.x = pk2bf(a0, a1);
        pk.y = pk2bf(a2, a3);
        *(uint2*)&bufN[r * SA + FFdim + lane * 4] = pk;

        // coord_out = coord + sum(wd)
        float sx = 0.f, sy = 0.f, sz = 0.f;
        for (int jj = o0 + lane; jj < o1; jj += 64) {
            float4 t = wd[(size_t)b * EE + jj];
            sx += t.x; sy += t.y; sz += t.z;
        }
#pragma unroll
        for (int m = 1; m < 64; m <<= 1) {
            sx += __shfl_xor(sx, m, 64);
            sy += __shfl_xor(sy, m, 64);
            sz += __shfl_xor(sz, m, 64);
        }
        if (lane < 3) {
            const size_t cb = ((size_t)b * NN + n) * 3 + lane;
            float s = (lane == 0) ? sx : (lane == 1) ? sy : sz;
            coord_out[cb] = coord[cb] + s;
        }
    }
    __syncthreads();

    // GEMM-A: [h|agg][32 x 384] @ nw1T -> mid[32 x 256], silu (pi-packed store)
    floatx4 acc[2][4];
#pragma unroll
    for (int i = 0; i < 2; ++i)
#pragma unroll
        for (int j = 0; j < 4; ++j)
#pragma unroll
            for (int q = 0; q < 4; ++q) acc[i][j][q] = 0.f;
#pragma unroll
    for (int ks = 0; ks < 12; ++ks) {
        const int kb = ks * 32 + koff;
        bf16x8 a[2], bfr[4];
#pragma unroll
        for (int rt = 0; rt < 2; ++rt)
            a[rt] = *(const bf16x8*)&bufN[(rt * 16 + lm) * SA + kb];
#pragma unroll
        for (int ct = 0; ct < 4; ++ct)
            bfr[ct] = *(const bf16x8*)&nw1T[(size_t)(w * 64 + ct * 16 + lm) * 384 + kb];
#pragma unroll
        for (int rt = 0; rt < 2; ++rt)
#pragma unroll
            for (int ct = 0; ct < 4; ++ct)
                acc[rt][ct] = __builtin_amdgcn_mfma_f32_16x16x32_bf16(
                    a[rt], bfr[ct], acc[rt][ct], 0, 0, 0);
    }
    float nb1v[4];
#pragma unroll
    for (int ct = 0; ct < 4; ++ct) nb1v[ct] = nb1[w * 64 + ct * 16 + lm];
    __syncthreads();   // A dead; overlay mid (stride SM, pi-permuted)
#pragma unroll
    for (int rt = 0; rt < 2; ++rt)
#pragma unroll
        for (int reg = 0; reg < 4; ++reg) {
            const int row = rt * 16 + quad * 4 + reg;
            uint2 pk;
            pk.x = pk2bf(silu_f(acc[rt][0][reg] + nb1v[0]),
                         silu_f(acc[rt][1][reg] + nb1v[1]));
            pk.y = pk2bf(silu_f(acc[rt][2][reg] + nb1v[2]),
                         silu_f(acc[rt][3][reg] + nb1v[3]));
            *(uint2*)&bufN[row * SM + w * 64 + lm * 4] = pk;
        }
    __syncthreads();

    // GEMM-B: mid[32 x 256] @ nw2T -> out[32 x 128] + bias + residual
    floatx4 accb[2][2];
#pragma unroll
    for (int i = 0; i < 2; ++i)
#pragma unroll
        for (int j = 0; j < 2; ++j)
#pragma unroll
            for (int q = 0; q < 4; ++q) accb[i][j][q] = 0.f;
#pragma unroll
    for (int ks = 0; ks < 8; ++ks) {
        const int kb = ks * 32 + koff;
        bf16x8 a[2], bfr[2];
#pragma unroll
        for (int rt = 0; rt < 2; ++rt)
            a[rt] = *(const bf16x8*)&bufN[(rt * 16 + lm) * SM + kb];
#pragma unroll
        for (int ct = 0; ct < 2; ++ct)
            bfr[ct] = *(const bf16x8*)&nw2T[(size_t)(w * 32 + ct * 16 + lm) * 256 + kb];
#pragma unroll
        for (int rt = 0; rt < 2; ++rt)
#pragma unroll
            for (int ct = 0; ct < 2; ++ct)
                accb[rt][ct] = __builtin_amdgcn_mfma_f32_16x16x32_bf16(
                    a[rt], bfr[ct], accb[rt][ct], 0, 0, 0);
    }
#pragma unroll
    for (int ct = 0; ct < 2; ++ct) {
        const int col = w * 32 + ct * 16 + lm;
        const float bias = nb2[col];
#pragma unroll
        for (int rt = 0; rt < 2; ++rt)
#pragma unroll
            for (int reg = 0; reg < 4; ++reg) {
                const int row = rt * 16 + quad * 4 + reg;
                const size_t gi = ((size_t)b * NN + n0 + row) * FFdim + col;
                hout[gi] = accb[rt][ct][reg] + bias + h[gi];
            }
    }
}

// ---------------------------------------------------------------------------
extern "C" void kernel_launch(void* const* d_in, const int* in_sizes, int n_in,
                              void* d_out, int out_size, void* d_ws, size_t ws_size,
                              hipStream_t stream) {
    const float* h     = (const float*)d_in[0];
    const float* coord = (const float*)d_in[1];
    const int*   eidx  = (const int*)d_in[2];
    const float* w1    = (const float*)d_in[3];
    const float* b1    = (const float*)d_in[4];
    const float* w2    = (const float*)d_in[5];
    const float* b2    = (const float*)d_in[6];
    const float* lng   = (const float*)d_in[7];
    const float* lnb   = (const float*)d_in[8];
    const float* nw1   = (const float*)d_in[9];
    const float* nb1   = (const float*)d_in[10];
    const float* nw2   = (const float*)d_in[11];
    const float* nb2   = (const float*)d_in[12];
    const float* cw1   = (const float*)d_in[13];
    const float* cb1   = (const float*)d_in[14];
    const float* cw2   = (const float*)d_in[15];

    float* hout = (float*)d_out;
    float* coord_out = hout + (size_t)BB * NN * FFdim;

    char* p = (char*)d_ws;
    float4* wd = (float4*)p;                   p += (size_t)BB * EE * 16;          // 4 MB
    unsigned short* efb = (unsigned short*)p;  p += (size_t)BB * EE * HHdim * 2;   // 134 MB
    unsigned short* hbf = (unsigned short*)p;  p += (size_t)HBF_ELEMS * 2;         // 4 MB
    unsigned short* w1T = (unsigned short*)p;  p += (size_t)W1T_ELEMS * 2;
    unsigned short* w2T = (unsigned short*)p;  p += (size_t)W2T_ELEMS * 2;
    unsigned short* cw1T = (unsigned short*)p; p += (size_t)CW1T_ELEMS * 2;
    unsigned short* nw1T = (unsigned short*)p; p += (size_t)NW1T_ELEMS * 2;
    unsigned short* nw2T = (unsigned short*)p; p += (size_t)NW2T_ELEMS * 2;
    int* counts = (int*)p;                     p += (size_t)NN * 4;
    int* offsets = (int*)p;                    p += (size_t)(NN + 1) * 4;
    int* cursor = (int*)p;                     p += (size_t)NN * 4;
    int* perm = (int*)p;                       p += (size_t)EE * 4;

    hipLaunchKernelGGL(prep_weights, dim3((WT_G + 255) / 256), dim3(256),
                       0, stream, w1, w2, cw1, nw1, nw2, h,
                       w1T, w2T, cw1T, nw1T, nw2T, hbf, counts);
    hipLaunchKernelGGL(csr_count, dim3(EE / 256), dim3(256), 0, stream, eidx, counts);
    hipLaunchKernelGGL(csr_scan, dim3(1), dim3(256), 0, stream, counts, offsets, cursor);
    hipLaunchKernelGGL(csr_fill, dim3(EE / 256), dim3(256), 0, stream, eidx, cursor, perm);
    hipLaunchKernelGGL(edge_kernel, dim3(EE / TE, BB), dim3(256), 0, stream,
                       hbf, coord, eidx, perm, w1T, b1, w2T, b2, lng, lnb, cw1T, cb1, cw2,
                       efb, wd);
    hipLaunchKernelGGL(node_kernel, dim3(NN / NT, BB), dim3(256), 0, stream,
                       h, hbf, coord, efb, wd, offsets, nw1T, nb1, nw2T, nb2,
                       hout, coord_out);
}